// Round 4
// baseline (33202.191 us; speedup 1.0000x reference)
//
#include <hip/hip_runtime.h>
#include <cstdint>

#define NREG 512
#define NBLK 8
#define NTHR 512

typedef unsigned long long u64;
typedef unsigned int u32;

// H(I, a, b, d, big_c) exactly per reference (f32)
__device__ __forceinline__ float Hfun(float I, float a, float b, float d, float bigc) {
    float x = a * I - b;
    float numer = fabsf(x) + 1e-9f;
    float neg = -d * x;
    float denom;
    if (neg > 50.0f) {
        denom = fabsf(1.0f - bigc * neg) + 1e-9f * d;
    } else {
        denom = fabsf(1.0f - expf(fminf(neg, 51.0f))) + 1e-9f * d;
    }
    return numer / denom;
}

__global__ __launch_bounds__(NTHR, 1)
void rww_kernel(const float* __restrict__ init_state,
                const float* __restrict__ Con,
                const float* __restrict__ v_of_T,
                float* __restrict__ out,      // f32: [512*2 state_vals][nsteps*512*2 hist]
                u64* __restrict__ xslot,      // d_ws: 2 * 512 u64 (tag<<32 | value)
                int nsteps)
{
    __shared__ __align__(16) float buf[2][NREG];   // S_E ping-pong by step parity

    const int tid = threadIdx.x;
    const int w   = tid >> 6;          // wave 0..7
    const int l   = tid & 63;
    const int s   = l & 7;             // column slice (64 cols each)
    const int rl  = l >> 3;            // row within wave
    const int b   = blockIdx.x;
    const int row = b * 64 + w * 8 + rl;
    const int rot = s << 1;            // LDS bank-spread rotation

    float2* __restrict__ state2 = reinterpret_cast<float2*>(out);              // [512]
    float2* __restrict__ hist2  = reinterpret_cast<float2*>(out + 2 * NREG);   // [nsteps*512]

    // ---- Con fragment into registers, pre-rotated: iteration j pairs cw[j]
    // with S_E[s*64 + ((j+rot)&15)*4 .. +4) ----
    float4 cw[16];
#pragma unroll
    for (int k = 0; k < 16; ++k) {
        int c = s * 64 + (((k + rot) & 15) << 2);
        cw[k] = *reinterpret_cast<const float4*>(Con + (size_t)row * NREG + c);
    }
    // pin in VGPRs: value becomes asm-defined, compiler cannot re-load from memory
#pragma unroll
    for (int k = 0; k < 16; ++k)
        asm volatile("" : "+v"(cw[k].x), "+v"(cw[k].y), "+v"(cw[k].z), "+v"(cw[k].w));

    // ---- initial state ----
    buf[0][tid] = init_state[2 * tid];         // S_E(0) for region tid
    float sEo  = init_state[2 * row];
    float sIo  = init_state[2 * row + 1];
    float vcur = v_of_T[row];                  // v[0][row]
    __syncthreads();

    for (int t = 0; t < nsteps; ++t) {
        // prefetch next step's noise (off critical path)
        float vnext = 0.f;
        if (t + 1 < nsteps) vnext = v_of_T[(size_t)(t + 1) * NREG + row];

        // ---- matvec: row 'row', columns [s*64, s*64+64), rotated reads ----
        const int p = t & 1;
        const float* sb = &buf[p][s << 6];
        float a0 = 0.f, a1 = 0.f, a2 = 0.f, a3 = 0.f;
#pragma unroll
        for (int j = 0; j < 16; ++j) {
            float4 sv = *reinterpret_cast<const float4*>(sb + (((j + rot) & 15) << 2));
            a0 = fmaf(cw[j].x, sv.x, a0);
            a1 = fmaf(cw[j].y, sv.y, a1);
            a2 = fmaf(cw[j].z, sv.z, a2);
            a3 = fmaf(cw[j].w, sv.w, a3);
        }
        float net = (a0 + a1) + (a2 + a3);
        net += __shfl_xor(net, 1, 64);
        net += __shfl_xor(net, 2, 64);
        net += __shfl_xor(net, 4, 64);         // all 8 slice-lanes now hold full row sum

        // ---- E side first: publish ASAP ----
        float I_E = 0.382f + 0.21f * sEo + 3.0f * net - sIo;
        float rE  = Hfun(I_E, 310.0f, 125.0f, 0.16f, 1.0e9f);
        float dSE = -sEo * 0.01f + (1.0f - sEo) * 0.000641f * rE + 0.01f * vcur;
        float sEn = sEo + 1e-4f * dSE;

        const int pn = (t + 1) & 1;
        u64 pk = ((u64)(u32)(t + 1) << 32) | (u64)__float_as_uint(sEn);
        if (s == 0) {
            __hip_atomic_store(&xslot[pn * NREG + row], pk,
                               __ATOMIC_RELAXED, __HIP_MEMORY_SCOPE_AGENT);
            buf[pn][row] = sEn;                // own rows bypass LLC round trip
        }

        // ---- I side + history (off critical path) ----
        float I_I = 0.2674f + 0.15f * sEo - sIo;
        float rI  = Hfun(I_I, 615.0f, 177.0f, 0.087f, 1.0e5f);
        float dSI = -sIo * 0.1f + 0.001f * rI + 0.01f * vcur;
        float sIn = sIo + 1e-4f * dSI;
        if (s == 0) {
            hist2[(size_t)t * NREG + row] = make_float2(sEn, sIn);
            if (t == nsteps - 1) state2[row] = make_float2(sEn, sIn);
        }
        sEo = sEn; sIo = sIn; vcur = vnext;

        // ---- gather remote S_E(t+1): thread tid owns slot tid ----
        if (t + 1 < nsteps && (tid >> 6) != b) {
            u64* slot = &xslot[pn * NREG + tid];
            const u32 want = (u32)(t + 1);
            u64 pk2;
            int spins = 0;
            for (;;) {
                pk2 = __hip_atomic_load(slot, __ATOMIC_RELAXED, __HIP_MEMORY_SCOPE_AGENT);
                if ((u32)(pk2 >> 32) == want) break;
                if (++spins > 256) {           // livelock insurance: back off, let stores land
                    __builtin_amdgcn_s_sleep(2);
                    spins = 0;
                }
            }
            buf[pn][tid] = __uint_as_float((u32)pk2);
        }

        // raw barrier: order LDS only — do NOT drain vmcnt (stores stay in flight)
        asm volatile("s_waitcnt lgkmcnt(0)" ::: "memory");
        __builtin_amdgcn_s_barrier();
    }
}

extern "C" void kernel_launch(void* const* d_in, const int* in_sizes, int n_in,
                              void* d_out, int out_size, void* d_ws, size_t ws_size,
                              hipStream_t stream) {
    const float* init_state = (const float*)d_in[0];
    const float* Con        = (const float*)d_in[1];
    const float* v_of_T     = (const float*)d_in[2];
    int nsteps = in_sizes[2] / NREG;   // 20000

    rww_kernel<<<dim3(NBLK), dim3(NTHR), 0, stream>>>(
        init_state, Con, v_of_T, (float*)d_out, (u64*)d_ws, nsteps);
}

// Round 6
// 28974.344 us; speedup vs baseline: 1.1459x; 1.1459x over previous
//
#include <hip/hip_runtime.h>
#include <cstdint>

#define NREG    512
#define NTHR    512
#define NWORK   8
#define NLAUNCH 256
#define FAST_TRIES 1024
#define ELECT_TRIES (1 << 20)

typedef unsigned long long u64;
typedef unsigned int u32;

// H(I, a, b, d, big_c) exactly per reference (f32)
__device__ __forceinline__ float Hfun(float I, float a, float b, float d, float bigc) {
    float x = a * I - b;
    float numer = fabsf(x) + 1e-9f;
    float neg = -d * x;
    float denom;
    if (neg > 50.0f) denom = fabsf(1.0f - bigc * neg) + 1e-9f * d;
    else             denom = fabsf(1.0f - expf(fminf(neg, 51.0f))) + 1e-9f * d;
    return numer / denom;
}

// L1-bypassed, L2-served accesses (intra-XCD coherent fast path)
__device__ __forceinline__ u32 load_u32_sc0(const u32* p) {
    u32 v;
    asm volatile("global_load_dword %0, %1, off sc0\n\t"
                 "s_waitcnt vmcnt(0)"
                 : "=v"(v) : "v"(p) : "memory");
    return v;
}
__device__ __forceinline__ void store_u32_sc0(u32* p, u32 v) {
    asm volatile("global_store_dword %0, %1, off sc0"
                 :: "v"(p), "v"(v) : "memory");
}

__global__ __launch_bounds__(NTHR, 1)
void rww_kernel(const float* __restrict__ init_state,
                const float* __restrict__ Con,
                const float* __restrict__ v_of_T,
                float* __restrict__ out,
                void* __restrict__ wsv,
                int nsteps)
{
    char* wsb   = (char*)wsv;
    u32* cnt    = (u32*)wsb;            // [8] per-XCD ticket counters (memset 0)
    u32* winner = (u32*)(wsb + 32);     // 0 = unset, else xcd+1
    u64* slow   = (u64*)(wsb + 64);     // [2][512] agent-scope tagged (LLC path)
    u32* fast   = (u32*)(wsb + 8256);   // [2][512] sc0 tagged-f32 (intra-XCD L2 path)

    __shared__ u32 sel;                 // low 8 bits: wid or 0xFF; bit 8: force-slow
    __shared__ __align__(16) float buf[2][NREG];

    const int tid = threadIdx.x;

    // ---- elect 8 co-XCD worker blocks (bounded; fallback = blocks 0..7, slow) ----
    if (tid == 0) {
        u32 xcc;
        asm volatile("s_getreg_b32 %0, hwreg(HW_REG_XCC_ID, 0, 32)" : "=s"(xcc));
        xcc &= 7u;
        u32 tick = atomicAdd(&cnt[xcc], 1u);                 // wait-free, all blocks
        if (tick == NWORK - 1) atomicCAS(winner, 0u, xcc + 1u);
        u32 wv = 0; int tries = 0;
        for (;;) {
            wv = __hip_atomic_load(winner, __ATOMIC_RELAXED, __HIP_MEMORY_SCOPE_AGENT);
            if (wv != 0u) break;
            if (++tries > ELECT_TRIES) break;                // bounded: no hang
            if ((tries & 63) == 0) __builtin_amdgcn_s_sleep(2);
        }
        u32 r;
        if (wv != 0u) r = (xcc == wv - 1u && tick < NWORK) ? tick : 0xFFu;
        else          r = (blockIdx.x < NWORK) ? (blockIdx.x | 0x100u) : 0xFFu;
        sel = r;
    }
    __syncthreads();
    const u32 selv = sel;
    if ((selv & 0xFFu) == 0xFFu) return;
    const u32 wid = selv & 0xFFu;
    bool useSlow = (selv & 0x100u) != 0u;

    const int w   = tid >> 6;          // wave 0..7
    const int l   = tid & 63;
    const int s   = l & 7;             // column slice (64 cols)
    const int rl  = l >> 3;            // row within wave
    const int row = (int)wid * 64 + w * 8 + rl;
    const int rot = s << 1;            // LDS bank-spread rotation

    float2* state2 = reinterpret_cast<float2*>(out);              // [512]
    float2* hist2  = reinterpret_cast<float2*>(out + 2 * NREG);   // [nsteps*512]
    const float4* conrow = reinterpret_cast<const float4*>(Con + (size_t)row * NREG);

    buf[0][tid] = init_state[2 * tid];
    float sEo  = init_state[2 * row];
    float sIo  = init_state[2 * row + 1];
    float vcur = v_of_T[row];
    __syncthreads();

    for (int t = 0; t < nsteps; ++t) {
        float vnext = 0.f;
        if (t + 1 < nsteps) vnext = v_of_T[(size_t)(t + 1) * NREG + row];

        // ---- matvec: row 'row', columns [s*64, s*64+64), rotated ----
        const int p = t & 1;
        const float* sb = &buf[p][s << 6];
        float a0 = 0.f, a1 = 0.f, a2 = 0.f, a3 = 0.f;
#pragma unroll
        for (int j = 0; j < 16; ++j) {
            int jj = (j + rot) & 15;
            float4 cv = conrow[(s << 4) + jj];
            float4 sv = *reinterpret_cast<const float4*>(sb + (jj << 2));
            a0 = fmaf(cv.x, sv.x, a0);
            a1 = fmaf(cv.y, sv.y, a1);
            a2 = fmaf(cv.z, sv.z, a2);
            a3 = fmaf(cv.w, sv.w, a3);
        }
        float net = (a0 + a1) + (a2 + a3);
        net += __shfl_xor(net, 1, 64);
        net += __shfl_xor(net, 2, 64);
        net += __shfl_xor(net, 4, 64);

        // ---- E side first: publish ASAP ----
        float I_E = 0.382f + 0.21f * sEo + 3.0f * net - sIo;
        float rE  = Hfun(I_E, 310.0f, 125.0f, 0.16f, 1.0e9f);
        float dSE = -sEo * 0.01f + (1.0f - sEo) * 0.000641f * rE + 0.01f * vcur;
        float sEn = sEo + 1e-4f * dSE;

        const int pn = (t + 1) & 1;
        if (s == 0) {
            // fast: f32 with low-4 mantissa bits = step tag (single dword: no tearing;
            // max inter-block skew is 1 step, so mod-16 tag cannot false-match)
            u32 fb = (__float_as_uint(sEn) & ~0xFu) | ((u32)(t + 1) & 0xFu);
            store_u32_sc0(&fast[pn * NREG + row], fb);
            // slow backstop: full 32-bit tag + exact value, agent scope
            u64 pk = ((u64)(u32)(t + 1) << 32) | (u64)__float_as_uint(sEn);
            __hip_atomic_store(&slow[pn * NREG + row], pk,
                               __ATOMIC_RELAXED, __HIP_MEMORY_SCOPE_AGENT);
            buf[pn][row] = sEn;            // own rows direct to LDS
        }

        // ---- I side + history (off critical path) ----
        float I_I = 0.2674f + 0.15f * sEo - sIo;
        float rI  = Hfun(I_I, 615.0f, 177.0f, 0.087f, 1.0e5f);
        float dSI = -sIo * 0.1f + 0.001f * rI + 0.01f * vcur;
        float sIn = sIo + 1e-4f * dSI;
        if (s == 0) {
            hist2[(size_t)t * NREG + row] = make_float2(sEn, sIn);
            if (t == nsteps - 1) state2[row] = make_float2(sEn, sIn);
        }
        sEo = sEn; sIo = sIn; vcur = vnext;

        // ---- gather remote S_E(t+1): thread tid owns slot tid ----
        if (t + 1 < nsteps && (u32)w != wid) {
            float val = 0.f; bool got = false;
            if (!useSlow) {
                const u32 want4 = (u32)(t + 1) & 0xFu;
                int tries = 0;
                for (;;) {
                    u32 bits = load_u32_sc0(&fast[pn * NREG + tid]);
                    if ((bits & 0xFu) == want4) { val = __uint_as_float(bits); got = true; break; }
                    if (++tries > FAST_TRIES) { useSlow = true; break; }   // sticky fallback
                }
            }
            if (!got) {
                const u32 want = (u32)(t + 1);
                u64 pk2;
                int spins = 0;
                for (;;) {
                    pk2 = __hip_atomic_load(&slow[pn * NREG + tid],
                                            __ATOMIC_RELAXED, __HIP_MEMORY_SCOPE_AGENT);
                    if ((u32)(pk2 >> 32) == want) break;
                    if (++spins > 256) { __builtin_amdgcn_s_sleep(2); spins = 0; }
                }
                val = __uint_as_float((u32)pk2);
            }
            buf[pn][tid] = val;
        }

        // raw barrier: order LDS only — stores stay in flight
        asm volatile("s_waitcnt lgkmcnt(0)" ::: "memory");
        __builtin_amdgcn_s_barrier();
        asm volatile("" ::: "memory");
    }
}

extern "C" void kernel_launch(void* const* d_in, const int* in_sizes, int n_in,
                              void* d_out, int out_size, void* d_ws, size_t ws_size,
                              hipStream_t stream) {
    const float* init_state = (const float*)d_in[0];
    const float* Con        = (const float*)d_in[1];
    const float* v_of_T     = (const float*)d_in[2];
    int nsteps = in_sizes[2] / NREG;   // 20000

    hipMemsetAsync(d_ws, 0, 16384, stream);   // tickets + winner + slots
    rww_kernel<<<dim3(NLAUNCH), dim3(NTHR), 0, stream>>>(
        init_state, Con, v_of_T, (float*)d_out, d_ws, nsteps);
}